// Round 12
// baseline (377.752 us; speedup 1.0000x reference)
//
#include <hip/hip_runtime.h>
#include <cstdint>
#include <cstddef>

#define DEV static __device__ __forceinline__

typedef float f32x4 __attribute__((ext_vector_type(4)));
typedef unsigned short u16x8 __attribute__((ext_vector_type(8)));

DEV unsigned short f2bf(float f){
  unsigned int u = __builtin_bit_cast(unsigned int, f);
  u += 0x7fffu + ((u >> 16) & 1u);
  return (unsigned short)(u >> 16);
}
DEV float bf2f(unsigned short h){
  unsigned int u = ((unsigned int)h) << 16;
  return __builtin_bit_cast(float, u);
}
DEV f32x4 mfma16(u16x8 a, u16x8 b, f32x4 c){
  asm("v_mfma_f32_16x16x32_bf16 %0, %1, %2, %0" : "+&v"(c) : "v"(a), "v"(b));
  return c;
}
DEV float wredsum(float v){
  #pragma unroll
  for (int m = 1; m < 64; m <<= 1) v += __shfl_xor(v, m, 64);
  return v;
}
DEV void load8(const float* src, float* x){
  f32x4 a = *(const f32x4*)src, b = *(const f32x4*)(src + 4);
  x[0]=a[0]; x[1]=a[1]; x[2]=a[2]; x[3]=a[3];
  x[4]=b[0]; x[5]=b[1]; x[6]=b[2]; x[7]=b[3];
}
DEV void store8(float* dst, const float* x){
  f32x4 a = {x[0],x[1],x[2],x[3]};
  f32x4 b = {x[4],x[5],x[6],x[7]};
  *(f32x4*)dst = a; *(f32x4*)(dst + 4) = b;
}
DEV u16x8 pack8(const float* x){
  u16x8 v;
  #pragma unroll
  for (int e = 0; e < 8; ++e) v[e] = f2bf(x[e]);
  return v;
}
// wave-cooperative layernorm over a 512-wide row; each lane holds 8 elems at cols c8..c8+7
DEV void ln8(float* x, const float* g, const float* b, int c8){
  float s = 0.f, ss = 0.f;
  #pragma unroll
  for (int e = 0; e < 8; ++e){ s += x[e]; ss += x[e]*x[e]; }
  s = wredsum(s); ss = wredsum(ss);
  float mean = s * (1.f/512.f);
  float rs = rsqrtf(ss * (1.f/512.f) - mean*mean + 1e-5f);
  f32x4 g0 = *(const f32x4*)(g + c8), g1 = *(const f32x4*)(g + c8 + 4);
  f32x4 b0 = *(const f32x4*)(b + c8), b1 = *(const f32x4*)(b + c8 + 4);
  #pragma unroll
  for (int e = 0; e < 4; ++e){
    x[e]   = (x[e]   - mean) * rs * g0[e] + b0[e];
    x[e+4] = (x[e+4] - mean) * rs * g1[e] + b1[e];
  }
}

// ---------------- K01: fused weight transpose + slots init + k1 features pass ----------------
// Three fully-independent work classes merged into one dispatch (blockIdx.y = seg).
// k1 cross-wave reduction is STAGED (2 waves at a time) but keeps the exact
// left-to-right addition order of the original  s += red[w2]  loop -> bit-identical.
// LDS union is 48 KB. NOTE: plain __launch_bounds__(512) — round 10's (512,6)
// capped VGPRs at 40 and spilled acc[8][8] to scratch (170 us, +45 MB writes).
struct K0Args {
  const float* src[9];
  unsigned short* dst[9];
  int K[9], N[9];
  const float* mu; const float* ls; const float* noise; float* S0;
  const float* features; const float* prev_attn;
  const float* g_in; const float* b_in; float* pf_part;
};

__global__ __launch_bounds__(512) void k01_kernel(K0Args a){
  __shared__ union {
    float tile[64][65];                                   // 16.6 KB (transpose)
    struct { float red2[2][8][512]; float tmp[8][512]; } r; // 32 + 16 = 48 KB (k1)
  } sm;
  int seg = blockIdx.y;
  int tid = threadIdx.x;
  if (seg < 9){
    // weight transpose: [K][N] fp32 -> [N][K] bf16 (512 threads, elementwise)
    int K = a.K[seg], N = a.N[seg];
    int tpn = N >> 6;
    int tiles = (K >> 6) * tpn;
    int t = blockIdx.x;
    if (t >= tiles) return;
    int k0 = (t / tpn) << 6, n0 = (t % tpn) << 6;
    const float* src = a.src[seg];
    #pragma unroll
    for (int i = 0; i < 8; ++i){
      int idx = tid + (i << 9);
      int r = idx >> 6, c = idx & 63;
      sm.tile[r][c] = src[(size_t)(k0 + r) * N + n0 + c];
    }
    __syncthreads();
    unsigned short* dst = a.dst[seg];
    #pragma unroll
    for (int i = 0; i < 8; ++i){
      int idx = tid + (i << 9);
      int r = idx >> 6, c = idx & 63;
      dst[(size_t)(n0 + r) * K + k0 + c] = f2bf(sm.tile[c][r]);
    }
  } else if (seg == 9){
    // slots init: S0 = mu + exp(log_sigma) * noise (256-thread mapping preserved)
    if (tid >= 256) return;
    long idx0 = ((long)blockIdx.x << 11) + ((long)tid << 3);
    if (idx0 >= 131072) return;
    int d0 = (int)(idx0 & 511);
    #pragma unroll
    for (int e = 0; e < 8; ++e){
      a.S0[idx0 + e] = a.mu[d0 + e] + expf(a.ls[d0 + e]) * a.noise[idx0 + e];
    }
  } else {
    // k1: features layernorm + pa-weighted partial sums (math round-7 verbatim;
    // cross-wave reduce staged in ascending-wave order -> bit-identical)
    if (blockIdx.x >= 256) return;
    int w = tid >> 6, lane = tid & 63;
    int b = blockIdx.x >> 3, sege = blockIdx.x & 7;
    int c8 = lane << 3;
    float gv[8], bv[8];
    #pragma unroll
    for (int e = 0; e < 8; ++e){ gv[e] = a.g_in[c8 + e]; bv[e] = a.b_in[c8 + e]; }
    float acc[8][8];
    #pragma unroll
    for (int p = 0; p < 8; ++p)
      #pragma unroll
      for (int e = 0; e < 8; ++e) acc[p][e] = 0.f;

    for (int rr = 0; rr < 16; ++rr){
      int j = (sege << 7) + (rr << 3) + w;
      const float* fr = a.features + ((size_t)(b << 10) + j) * 512 + c8;
      float x[8]; load8(fr, x);
      float s = 0.f, ss = 0.f;
      #pragma unroll
      for (int e = 0; e < 8; ++e){ s += x[e]; ss += x[e]*x[e]; }
      s = wredsum(s); ss = wredsum(ss);
      float mean = s * (1.f/512.f);
      float rs = rsqrtf(ss * (1.f/512.f) - mean*mean + 1e-5f);
      float y[8];
      #pragma unroll
      for (int e = 0; e < 8; ++e) y[e] = (x[e] - mean) * rs * gv[e] + bv[e];
      const float* par = a.prev_attn + (((size_t)(b << 10) + j) << 3);
      f32x4 p0 = *(const f32x4*)par, p1 = *(const f32x4*)(par + 4);
      #pragma unroll
      for (int p = 0; p < 4; ++p)
        #pragma unroll
        for (int e = 0; e < 8; ++e) acc[p][e] += p0[p] * y[e];
      #pragma unroll
      for (int p = 0; p < 4; ++p)
        #pragma unroll
        for (int e = 0; e < 8; ++e) acc[p + 4][e] += p1[p] * y[e];
    }
    // staged reduce: stage st folds waves 2st, 2st+1 into tmp in ascending order.
    // tmp after st: (((r0+r1)+r2)+...+r(2st+1)  == original left-to-right chain.
    for (int st = 0; st < 4; ++st){
      if ((w >> 1) == st){
        int h = w & 1;
        #pragma unroll
        for (int p = 0; p < 8; ++p){
          f32x4 a0 = {acc[p][0], acc[p][1], acc[p][2], acc[p][3]};
          f32x4 a1 = {acc[p][4], acc[p][5], acc[p][6], acc[p][7]};
          *(f32x4*)&sm.r.red2[h][p][c8] = a0;
          *(f32x4*)&sm.r.red2[h][p][c8 + 4] = a1;
        }
      }
      __syncthreads();
      for (int t2 = tid; t2 < 4096; t2 += 512){
        int p = t2 >> 9, d = t2 & 511;
        float t = (st == 0) ? sm.r.red2[0][p][d]
                            : (sm.r.tmp[p][d] + sm.r.red2[0][p][d]);
        t = t + sm.r.red2[1][p][d];
        sm.r.tmp[p][d] = t;
      }
      __syncthreads();
    }
    for (int t2 = tid; t2 < 4096; t2 += 512){
      int p = t2 >> 9, d = t2 & 511;
      a.pf_part[((size_t)((b << 3) + sege) * 8 + p) * 512 + d] = sm.r.tmp[p][d];
    }
  }
}

// ---------------- K2: reduce pf, pv = pf@Wv, k_ = ln(prev_slots)@Wk ----------------
__global__ __launch_bounds__(512) void k2_kernel(
    const float* __restrict__ pf_part, const float* __restrict__ prev_slots,
    const float* __restrict__ g_ps, const float* __restrict__ b_ps,
    const unsigned short* __restrict__ wvT, const unsigned short* __restrict__ wkT,
    float* __restrict__ pv, float* __restrict__ kbuf)
{
  __shared__ unsigned short pfB[16][512];
  __shared__ unsigned short psB[16][512];
  int tid = threadIdx.x, w = tid >> 6, lane = tid & 63, c8 = lane << 3;
  int blk = blockIdx.x;
  for (int t2 = tid; t2 < 1024; t2 += 512){
    int r = t2 >> 6, c = t2 & 63;
    int b = (blk << 1) + (r >> 3), p = r & 7;
    f32x4 s0 = {0,0,0,0}, s1 = {0,0,0,0};
    #pragma unroll
    for (int sg = 0; sg < 8; ++sg){
      const float* src = pf_part + ((size_t)((b << 3) + sg) * 8 + p) * 512 + (c << 3);
      s0 += *(const f32x4*)src;
      s1 += *(const f32x4*)(src + 4);
    }
    u16x8 pk;
    #pragma unroll
    for (int e = 0; e < 4; ++e){ pk[e] = f2bf(s0[e]); pk[e + 4] = f2bf(s1[e]); }
    *(u16x8*)&pfB[r][(c ^ (r & 7)) << 3] = pk;
  }
  #pragma unroll
  for (int rr = 0; rr < 2; ++rr){
    int r = (w << 1) + rr;
    int b = (blk << 1) + (r >> 3), sl = r & 7;
    float x[8];
    load8(prev_slots + ((size_t)((b << 3) + sl) << 9) + c8, x);
    ln8(x, g_ps, b_ps, c8);
    *(u16x8*)&psB[r][(lane ^ (r & 7)) << 3] = pack8(x);
  }
  __syncthreads();
  int which = w >> 2;
  int nbase = (w & 3) << 7;
  const unsigned short* Wt = which ? wkT : wvT;
  int l15 = lane & 15, kb4 = lane >> 4;
  f32x4 acc[8];
  #pragma unroll
  for (int nf = 0; nf < 8; ++nf) acc[nf] = (f32x4){0,0,0,0};
  for (int ks = 0; ks < 16; ++ks){
    int chunk = (ks << 2) + kb4;
    int m = l15;
    u16x8 av = which ? *(const u16x8*)&psB[m][(chunk ^ (m & 7)) << 3]
                     : *(const u16x8*)&pfB[m][(chunk ^ (m & 7)) << 3];
    #pragma unroll
    for (int nf = 0; nf < 8; ++nf){
      int n = nbase + (nf << 4) + l15;
      u16x8 bv = *(const u16x8*)(Wt + (size_t)n * 512 + (ks << 5) + (kb4 << 3));
      acc[nf] = mfma16(av, bv, acc[nf]);
    }
  }
  float* dst = which ? kbuf : pv;
  #pragma unroll
  for (int nf = 0; nf < 8; ++nf)
    #pragma unroll
    for (int ri = 0; ri < 4; ++ri){
      int r = (kb4 << 2) + ri;
      int b = (blk << 1) + (r >> 3);
      dst[((size_t)((b << 3) + (r & 7)) << 9) + nbase + (nf << 4) + l15] = acc[nf][ri];
    }
}

// ---------------- KA: per-2-batch step head (round-7 verbatim) ----------------
__global__ __launch_bounds__(512) void ka_kernel(
    const float* __restrict__ Sin, int step,
    const float* __restrict__ gfin, const float* __restrict__ bfin,
    const float* __restrict__ gs, const float* __restrict__ bs,
    const float* __restrict__ gica, const float* __restrict__ bica,
    const float* __restrict__ ga, const float* __restrict__ ba,
    const unsigned short* __restrict__ wqT,
    const float* __restrict__ kbuf, const float* __restrict__ pvbuf,
    const float* __restrict__ prev_attn,
    float* __restrict__ S1, unsigned short* __restrict__ hA,
    float* __restrict__ attn_out)
{
  __shared__ unsigned short lnS[16][512];
  __shared__ float Sf[16][512];
  __shared__ float qf[16][512];
  __shared__ float dotsS[2][8][8];
  __shared__ float attnS[2][8][8];
  int tid = threadIdx.x, w = tid >> 6, lane = tid & 63, c8 = lane << 3;
  int blk = blockIdx.x;

  // phase 1: load + (ln_fin) + ln_s
  #pragma unroll
  for (int rr = 0; rr < 2; ++rr){
    int r = (w << 1) + rr;
    int b = (blk << 1) + (r >> 3), sl = r & 7;
    float x[8];
    load8(Sin + ((size_t)((b << 3) + sl) << 9) + c8, x);
    if (step > 0) ln8(x, gfin, bfin, c8);
    store8(&Sf[r][c8], x);
    float z[8];
    #pragma unroll
    for (int e = 0; e < 8; ++e) z[e] = x[e];
    ln8(z, gs, bs, c8);
    *(u16x8*)&lnS[r][(lane ^ (r & 7)) << 3] = pack8(z);
  }
  __syncthreads();

  // phase 2: q = lnS @ WqT  (each wave: 64 cols)
  {
    int n0 = w << 6, l15 = lane & 15, kb4 = lane >> 4;
    f32x4 acc[4];
    #pragma unroll
    for (int nf = 0; nf < 4; ++nf) acc[nf] = (f32x4){0,0,0,0};
    for (int ks = 0; ks < 16; ++ks){
      int m = l15, chunk = (ks << 2) + kb4;
      u16x8 av = *(const u16x8*)&lnS[m][(chunk ^ (m & 7)) << 3];
      #pragma unroll
      for (int nf = 0; nf < 4; ++nf){
        int n = n0 + (nf << 4) + l15;
        u16x8 bv = *(const u16x8*)(wqT + (size_t)n * 512 + (ks << 5) + (kb4 << 3));
        acc[nf] = mfma16(av, bv, acc[nf]);
      }
    }
    #pragma unroll
    for (int nf = 0; nf < 4; ++nf)
      #pragma unroll
      for (int ri = 0; ri < 4; ++ri)
        qf[(kb4 << 2) + ri][n0 + (nf << 4) + l15] = acc[nf][ri];
  }
  __syncthreads();

  // phase 3: dots = q . k_ * scale
  if (tid < 128){
    int bb = tid >> 6, i = (tid >> 3) & 7, j = tid & 7;
    int b = (blk << 1) + bb;
    const float* kr = kbuf + ((size_t)((b << 3) + j) << 9);
    const float* qr = &qf[(bb << 3) + i][0];
    float s = 0.f;
    for (int d = 0; d < 512; d += 4){
      f32x4 qv = *(const f32x4*)(qr + d);
      f32x4 kv = *(const f32x4*)(kr + d);
      s += qv[0]*kv[0] + qv[1]*kv[1] + qv[2]*kv[2] + qv[3]*kv[3];
    }
    dotsS[bb][i][j] = s * 0.044194173824159216f;
  }
  __syncthreads();

  // phase 4: softmax over slot axis (i), per (bb, j), + EPS
  if (tid < 16){
    int bb = tid >> 3, j = tid & 7;
    float mx = -1e30f;
    #pragma unroll
    for (int i = 0; i < 8; ++i) mx = fmaxf(mx, dotsS[bb][i][j]);
    float ex[8]; float sum = 0.f;
    #pragma unroll
    for (int i = 0; i < 8; ++i){ ex[i] = expf(dotsS[bb][i][j] - mx); sum += ex[i]; }
    float inv = 1.f / sum;
    #pragma unroll
    for (int i = 0; i < 8; ++i) attnS[bb][i][j] = ex[i] * inv + 1e-8f;
  }
  __syncthreads();

  // phase 5: renormalize over j
  if (tid < 16){
    int bb = tid >> 3, i = tid & 7;
    float s = 0.f;
    #pragma unroll
    for (int j = 0; j < 8; ++j) s += attnS[bb][i][j];
    float inv = 1.f / s;
    #pragma unroll
    for (int j = 0; j < 8; ++j) attnS[bb][i][j] *= inv;
  }
  __syncthreads();

  // phase 6: upd + S1 + hA
  #pragma unroll
  for (int rr = 0; rr < 2; ++rr){
    int r = (w << 1) + rr;
    int bb = r >> 3; int b = (blk << 1) + bb; int i = r & 7;
    float u[8];
    #pragma unroll
    for (int e = 0; e < 8; ++e) u[e] = 0.f;
    #pragma unroll
    for (int p = 0; p < 8; ++p){
      float ap = attnS[bb][i][p];
      const float* pvr = pvbuf + ((size_t)((b << 3) + p) << 9) + c8;
      f32x4 v0 = *(const f32x4*)pvr, v1 = *(const f32x4*)(pvr + 4);
      #pragma unroll
      for (int e = 0; e < 4; ++e){ u[e] += ap * v0[e]; u[e + 4] += ap * v1[e]; }
    }
    float x[8];
    #pragma unroll
    for (int e = 0; e < 8; ++e) x[e] = Sf[r][c8 + e] + u[e];
    ln8(x, gica, bica, c8);
    store8(S1 + ((size_t)((b << 3) + i) << 9) + c8, x);
    ln8(x, ga, ba, c8);
    *(u16x8*)(hA + ((size_t)((b << 3) + i) << 9) + c8) = pack8(x);
  }

  // phase 7: final attention map output: out[b][jhw][i] = sum_p attn[i][p] * prev_attn[b][jhw][p]
  if (attn_out){
    for (int t2 = tid; t2 < 2048; t2 += 512){
      int bb = t2 >> 10, jh = t2 & 1023;
      int b = (blk << 1) + bb;
      const float* par = prev_attn + (((size_t)(b << 10) + jh) << 3);
      f32x4 p0 = *(const f32x4*)par, p1 = *(const f32x4*)(par + 4);
      float o[8];
      #pragma unroll
      for (int i2 = 0; i2 < 8; ++i2){
        float s = 0.f;
        #pragma unroll
        for (int p = 0; p < 4; ++p){
          s += attnS[bb][i2][p] * p0[p];
          s += attnS[bb][i2][p + 4] * p1[p];
        }
        o[i2] = s;
      }
      float* dst = attn_out + (((size_t)(b << 10) + jh) << 3);
      store8(dst, o);
    }
  }
}

// ---------------- MHSA: per (batch, head), 8x8 attention over slots ----------------
__global__ __launch_bounds__(64) void mhsa_kernel(
    const unsigned short* __restrict__ qkv, unsigned short* __restrict__ ob)
{
  int b = blockIdx.x >> 3, h = blockIdx.x & 7;
  int lane = threadIdx.x;
  int i = lane >> 3, j = lane & 7;
  const unsigned short* qr = qkv + (size_t)((b << 3) + i) * 1536 + (h << 6);
  const unsigned short* kr = qkv + (size_t)((b << 3) + j) * 1536 + 512 + (h << 6);
  float s = 0.f;
  #pragma unroll
  for (int d0 = 0; d0 < 64; d0 += 8){
    u16x8 qv = *(const u16x8*)(qr + d0);
    u16x8 kv = *(const u16x8*)(kr + d0);
    #pragma unroll
    for (int e = 0; e < 8; ++e) s += bf2f(qv[e]) * bf2f(kv[e]);
  }
  s *= 0.125f;
  float mx = s;
  mx = fmaxf(mx, __shfl_xor(mx, 1, 64));
  mx = fmaxf(mx, __shfl_xor(mx, 2, 64));
  mx = fmaxf(mx, __shfl_xor(mx, 4, 64));
  float p = expf(s - mx);
  float den = p;
  den += __shfl_xor(den, 1, 64);
  den += __shfl_xor(den, 2, 64);
  den += __shfl_xor(den, 4, 64);
  float att = p / den;
  int dg = lane & 7;
  float acc[8];
  #pragma unroll
  for (int e = 0; e < 8; ++e) acc[e] = 0.f;
  #pragma unroll
  for (int jj = 0; jj < 8; ++jj){
    float av = __shfl(att, (lane & 56) | jj, 64);
    const unsigned short* vr = qkv + (size_t)((b << 3) + jj) * 1536 + 1024 + (h << 6) + (dg << 3);
    u16x8 vv = *(const u16x8*)vr;
    #pragma unroll
    for (int e = 0; e < 8; ++e) acc[e] += av * bf2f(vv[e]);
  }
  u16x8 o8;
  #pragma unroll
  for (int e = 0; e < 8; ++e) o8[e] = f2bf(acc[e]);
  *(u16x8*)(ob + (size_t)((b << 3) + i) * 512 + (h << 6) + (dg << 3)) = o8;
}

// ---------------- gemm16: 16-row tile, full-K in-thread (bit-identical K-order) ----------------
// AMODE: 0 = plain bf16 A [256][K]; 1 = layernorm from fp32 [256][512]
// EPMODE: 0 = bf16 store; 1 = bf16 + bias; 2 = fp32 resid + v + bias
// NF: n-fragments per wave (block covers 64*NF cols)
template<int AMODE, int EPMODE, int NF>
__global__ __launch_bounds__(256) void gemm16_kernel(
    const void* __restrict__ Asrc, const unsigned short* __restrict__ Wt,
    void* __restrict__ Cdst, const float* __restrict__ resid,
    const float* __restrict__ bias, const float* __restrict__ g,
    const float* __restrict__ bp, int N, int K)
{
  __shared__ unsigned short Alds[16][512];
  int tid = threadIdx.x, lane = tid & 63, w = tid >> 6, c8 = lane << 3;
  int m0 = blockIdx.y << 4;
  int n0g = blockIdx.x * (64 * NF);
  int l15 = lane & 15, kb4 = lane >> 4;
  f32x4 acc[NF];
  #pragma unroll
  for (int nf = 0; nf < NF; ++nf) acc[nf] = (f32x4){0,0,0,0};

  int nkc = K >> 9;
  for (int kc = 0; kc < nkc; ++kc){
    if (kc) __syncthreads();
    if (AMODE == 0){
      const unsigned short* A = (const unsigned short*)Asrc;
      #pragma unroll
      for (int rr = 0; rr < 4; ++rr){
        int r = (w << 2) + rr;
        u16x8 v = *(const u16x8*)(A + (size_t)(m0 + r) * K + (kc << 9) + c8);
        *(u16x8*)&Alds[r][(lane ^ (r & 7)) << 3] = v;
      }
    } else {
      const float* A = (const float*)Asrc;
      #pragma unroll
      for (int rr = 0; rr < 4; ++rr){
        int r = (w << 2) + rr;
        float x[8];
        load8(A + ((size_t)(m0 + r) << 9) + c8, x);
        ln8(x, g, bp, c8);
        *(u16x8*)&Alds[r][(lane ^ (r & 7)) << 3] = pack8(x);
      }
    }
    __syncthreads();
    const unsigned short* wbase = Wt + ((size_t)kc << 9);
    for (int ks = 0; ks < 16; ++ks){
      int chunk = (ks << 2) + kb4;
      u16x8 a0 = *(const u16x8*)&Alds[l15][(chunk ^ (l15 & 7)) << 3];
      #pragma unroll
      for (int nf = 0; nf < NF; ++nf){
        int n = n0g + w * (16 * NF) + (nf << 4) + l15;
        u16x8 bv = *(const u16x8*)(wbase + (size_t)n * K + (ks << 5) + (kb4 << 3));
        acc[nf] = mfma16(a0, bv, acc[nf]);
      }
    }
  }
  #pragma unroll
  for (int nf = 0; nf < NF; ++nf)
    #pragma unroll
    for (int ri = 0; ri < 4; ++ri){
      int m = m0 + (kb4 << 2) + ri;
      int c = n0g + w * (16 * NF) + (nf << 4) + l15;
      float v = acc[nf][ri];
      if (EPMODE == 0){
        ((unsigned short*)Cdst)[(size_t)m * N + c] = f2bf(v);
      } else if (EPMODE == 1){
        ((unsigned short*)Cdst)[(size_t)m * N + c] = f2bf(v + bias[c]);
      } else {
        ((float*)Cdst)[(size_t)m * N + c] = resid[(size_t)m * N + c] + v + bias[c];
      }
    }
}

// ---------------- ff2: full-K single-barrier; S3 = S2 + swiglu(hw1) @ Wff2 + bff2 ----------------
__global__ __launch_bounds__(256) void ff2_kernel(
    const unsigned short* __restrict__ hw1, const unsigned short* __restrict__ wff2T,
    float* __restrict__ S3, const float* __restrict__ S2, const float* __restrict__ bff2)
{
  __shared__ unsigned short Alds[16][2048]; // 64 KB
  int tid = threadIdx.x, lane = tid & 63, w = tid >> 6, c8 = lane << 3;
  int m0 = blockIdx.y << 4;
  int n0 = blockIdx.x << 6;

  #pragma unroll
  for (int kc = 0; kc < 4; ++kc){
    #pragma unroll
    for (int rr = 0; rr < 4; ++rr){
      int r = (w << 2) + rr;
      const unsigned short* ar = hw1 + (size_t)(m0 + r) * 4096 + (kc << 9) + c8;
      u16x8 uu = *(const u16x8*)ar;
      u16x8 gg = *(const u16x8*)(ar + 2048);
      u16x8 pk;
      #pragma unroll
      for (int e = 0; e < 8; ++e){
        float uv = bf2f(uu[e]), gv = bf2f(gg[e]);
        float sl = gv / (1.f + __expf(-gv));
        pk[e] = f2bf(uv * sl);
      }
      *(u16x8*)&Alds[r][(kc << 9) + ((lane ^ (r & 7)) << 3)] = pk;
    }
  }
  __syncthreads();

  int l15 = lane & 15, kb4 = lane >> 4;
  f32x4 acc = {0,0,0,0};
  for (int kk = 0; kk < 64; ++kk){
    int kc = kk >> 4, ks = kk & 15;
    int chunk = (ks << 2) + kb4;
    u16x8 a0 = *(const u16x8*)&Alds[l15][(kc << 9) + ((chunk ^ (l15 & 7)) << 3)];
    int n = n0 + (w << 4) + l15;
    u16x8 bv = *(const u16x8*)(wff2T + (size_t)n * 2048 + (kc << 9) + (ks << 5) + (kb4 << 3));
    acc = mfma16(a0, bv, acc);
  }
  #pragma unroll
  for (int ri = 0; ri < 4; ++ri){
    int m = m0 + (kb4 << 2) + ri;
    int c = n0 + (w << 4) + l15;
    S3[(size_t)m * 512 + c] = S2[(size_t)m * 512 + c] + acc[ri] + bff2[c];
  }
}

// ---------------- final: out_slots = ln(S3, g_fin, b_fin) ----------------
__global__ __launch_bounds__(512) void fin_kernel(
    const float* __restrict__ S3, const float* __restrict__ g,
    const float* __restrict__ bp, float* __restrict__ out)
{
  int tid = threadIdx.x, w = tid >> 6, lane = tid & 63, c8 = lane << 3;
  int row = (blockIdx.x << 3) + w;
  float x[8];
  load8(S3 + ((size_t)row << 9) + c8, x);
  ln8(x, g, bp, c8);
  store8(out + ((size_t)row << 9) + c8, x);
}

// ---------------- host ----------------
extern "C" void kernel_launch(void* const* d_in, const int* in_sizes, int n_in,
                              void* d_out, int out_size, void* d_ws, size_t ws_size,
                              hipStream_t stream)
{
  (void)in_sizes; (void)n_in; (void)out_size; (void)ws_size;
  const float* features       = (const float*)d_in[0];
  const float* prev_slots     = (const float*)d_in[1];
  const float* prev_attn      = (const float*)d_in[2];
  const float* init_noise     = (const float*)d_in[3];
  const float* init_mu        = (const float*)d_in[4];
  const float* init_log_sigma = (const float*)d_in[5];
  const float* Wk   = (const float*)d_in[6];
  const float* Wv   = (const float*)d_in[7];
  const float* Wq   = (const float*)d_in[8];
  const float* g_in = (const float*)d_in[9];
  const float* g_ps = (const float*)d_in[10];
  const float* g_s  = (const float*)d_in[11];
  const float* g_ica= (const float*)d_in[12];
  const float* g_a  = (const float*)d_in[13];
  const float* g_f  = (const float*)d_in[14];
  const float* g_fin= (const float*)d_in[15];
  const float* b_in = (const float*)d_in[16];
  const float* b_ps = (const float*)d_in[17];
  const float* b_s  = (const float*)d_in[18];
  const float* b_ica= (const float*)d_in[19];
  const float* b_a  = (const float*)d_in[20];
  const float* b_f  = (const float*)d_in[21];
  const float* b_fin= (const float*)d_in[22];
  const float* Waq  = (const float*)d_in[23];
  const float* Wak  = (const float*)d_in[24];
  const float* Wav  = (const float*)d_in[25];
  const float* Wao  = (const float*)d_in[26];
  const float* bao  = (const float*)d_in[27];
  const float* Wff1 = (const float*)d_in[28];
  const float* bff1 = (const float*)d_in[29];
  const float* Wff2 = (const float*)d_in[30];
  const float* bff2 = (const float*)d_in[31];

  char* wsb = (char*)d_ws;
  size_t off = 0;
  auto alloc = [&](size_t n) -> void* {
    void* p = wsb + off;
    off = (off + n + 255) & ~(size_t)255;
    return p;
  };
  unsigned short* wkT   = (unsigned short*)alloc(512 * 512 * 2);
  unsigned short* wvT   = (unsigned short*)alloc(512 * 512 * 2);
  unsigned short* wqT   = (unsigned short*)alloc(512 * 512 * 2);
  unsigned short* wqkvT = (unsigned short*)alloc((size_t)3 * 512 * 512 * 2); // waq|wak|wav
  unsigned short* waoT  = (unsigned short*)alloc(512 * 512 * 2);
  unsigned short* wff1T = (unsigned short*)alloc((size_t)4096 * 512 * 2);
  unsigned short* wff2T = (unsigned short*)alloc((size_t)512 * 2048 * 2);
  float* S0 = (float*)alloc((size_t)256 * 512 * 4);
  float* S3 = (float*)alloc((size_t)256 * 512 * 4);
  float* S1 = (float*)alloc((size_t)256 * 512 * 4);
  float* S2 = (float*)alloc((size_t)256 * 512 * 4);
  unsigned short* hA   = (unsigned short*)alloc((size_t)256 * 512 * 2);
  unsigned short* qkvB = (unsigned short*)alloc((size_t)256 * 1536 * 2);
  unsigned short* oB   = (unsigned short*)alloc((size_t)256 * 512 * 2);
  float* pfp = (float*)alloc((size_t)32 * 8 * 8 * 512 * 4);   // 4 MB; dead after k2
  unsigned short* hw1 = (unsigned short*)pfp;                 // alias: 256*4096*2 = 2 MB
  float* pvB = (float*)alloc((size_t)32 * 8 * 512 * 4);
  float* kB  = (float*)alloc((size_t)32 * 8 * 512 * 4);

  K0Args a{};
  a.src[0] = Wk;   a.dst[0] = wkT;                    a.K[0] = 512;  a.N[0] = 512;
  a.src[1] = Wv;   a.dst[1] = wvT;                    a.K[1] = 512;  a.N[1] = 512;
  a.src[2] = Wq;   a.dst[2] = wqT;                    a.K[2] = 512;  a.N[2] = 512;
  a.src[3] = Waq;  a.dst[3] = wqkvT;                  a.K[3] = 512;  a.N[3] = 512;
  a.src[4] = Wak;  a.dst[4] = wqkvT + 512 * 512;      a.K[4] = 512;  a.N[4] = 512;
  a.src[5] = Wav;  a.dst[5] = wqkvT + 2 * 512 * 512;  a.K[5] = 512;  a.N[5] = 512;
  a.src[6] = Wao;  a.dst[6] = waoT;                   a.K[6] = 512;  a.N[6] = 512;
  a.src[7] = Wff1; a.dst[7] = wff1T;                  a.K[7] = 512;  a.N[7] = 4096;
  a.src[8] = Wff2; a.dst[8] = wff2T;                  a.K[8] = 2048; a.N[8] = 512;
  a.mu = init_mu; a.ls = init_log_sigma; a.noise = init_noise; a.S0 = S0;
  a.features = features; a.prev_attn = prev_attn;
  a.g_in = g_in; a.b_in = b_in; a.pf_part = pfp;

  // fused prologue: weight transposes + slots init + k1 features pass (independent work)
  k01_kernel<<<dim3(512, 11), 512, 0, stream>>>(a);
  k2_kernel<<<16, 512, 0, stream>>>(pfp, prev_slots, g_ps, b_ps, wvT, wkT, pvB, kB);

  float* outSlots = (float*)d_out;
  float* outAttn  = (float*)d_out + 131072;

  for (int step = 0; step < 4; ++step){
    ka_kernel<<<16, 512, 0, stream>>>(step ? S3 : S0, step,
        g_fin, b_fin, g_s, b_s, g_ica, b_ica, g_a, b_a,
        wqT, kB, pvB, prev_attn, S1, hA,
        (step == 3) ? outAttn : (float*)nullptr);
    // qkv: [256,512] @ [512,1536] -> bf16 (16x64 tiles, 384 blocks)
    gemm16_kernel<0,0,1><<<dim3(24, 16), 256, 0, stream>>>(
        hA, wqkvT, qkvB, nullptr, nullptr, nullptr, nullptr, 1536, 512);
    mhsa_kernel<<<256, 64, 0, stream>>>(qkvB, oB);
    // ao: S2 = S1 + oB @ Wao + bao (64-wide tiles, 128 blocks)
    gemm16_kernel<0,2,1><<<dim3(8, 16), 256, 0, stream>>>(
        oB, waoT, S2, S1, bao, nullptr, nullptr, 512, 512);
    // ff1: ln(S2) @ [512,4096] + bff1 -> bf16 hw1 (16x64 tiles, 1024 blocks)
    gemm16_kernel<1,1,1><<<dim3(64, 16), 256, 0, stream>>>(
        S2, wff1T, hw1, nullptr, bff1, g_f, b_f, 4096, 512);
    // ff2: S3 = S2 + swiglu(hw1) @ [2048,512] + bff2 (full-K stage, 128 blocks)
    ff2_kernel<<<dim3(8, 16), 256, 0, stream>>>(hw1, wff2T, S3, S2, bff2);
  }
  fin_kernel<<<32, 512, 0, stream>>>(S3, g_fin, b_fin, outSlots);
}

// Round 13
// 374.175 us; speedup vs baseline: 1.0096x; 1.0096x over previous
//
#include <hip/hip_runtime.h>
#include <cstdint>
#include <cstddef>

#define DEV static __device__ __forceinline__

typedef float f32x4 __attribute__((ext_vector_type(4)));
typedef unsigned short u16x8 __attribute__((ext_vector_type(8)));

DEV unsigned short f2bf(float f){
  unsigned int u = __builtin_bit_cast(unsigned int, f);
  u += 0x7fffu + ((u >> 16) & 1u);
  return (unsigned short)(u >> 16);
}
DEV float bf2f(unsigned short h){
  unsigned int u = ((unsigned int)h) << 16;
  return __builtin_bit_cast(float, u);
}
DEV f32x4 mfma16(u16x8 a, u16x8 b, f32x4 c){
  asm("v_mfma_f32_16x16x32_bf16 %0, %1, %2, %0" : "+&v"(c) : "v"(a), "v"(b));
  return c;
}
DEV float wredsum(float v){
  #pragma unroll
  for (int m = 1; m < 64; m <<= 1) v += __shfl_xor(v, m, 64);
  return v;
}
DEV void load8(const float* src, float* x){
  f32x4 a = *(const f32x4*)src, b = *(const f32x4*)(src + 4);
  x[0]=a[0]; x[1]=a[1]; x[2]=a[2]; x[3]=a[3];
  x[4]=b[0]; x[5]=b[1]; x[6]=b[2]; x[7]=b[3];
}
DEV void store8(float* dst, const float* x){
  f32x4 a = {x[0],x[1],x[2],x[3]};
  f32x4 b = {x[4],x[5],x[6],x[7]};
  *(f32x4*)dst = a; *(f32x4*)(dst + 4) = b;
}
DEV u16x8 pack8(const float* x){
  u16x8 v;
  #pragma unroll
  for (int e = 0; e < 8; ++e) v[e] = f2bf(x[e]);
  return v;
}
// wave-cooperative layernorm over a 512-wide row; each lane holds 8 elems at cols c8..c8+7
DEV void ln8(float* x, const float* g, const float* b, int c8){
  float s = 0.f, ss = 0.f;
  #pragma unroll
  for (int e = 0; e < 8; ++e){ s += x[e]; ss += x[e]*x[e]; }
  s = wredsum(s); ss = wredsum(ss);
  float mean = s * (1.f/512.f);
  float rs = rsqrtf(ss * (1.f/512.f) - mean*mean + 1e-5f);
  f32x4 g0 = *(const f32x4*)(g + c8), g1 = *(const f32x4*)(g + c8 + 4);
  f32x4 b0 = *(const f32x4*)(b + c8), b1 = *(const f32x4*)(b + c8 + 4);
  #pragma unroll
  for (int e = 0; e < 4; ++e){
    x[e]   = (x[e]   - mean) * rs * g0[e] + b0[e];
    x[e+4] = (x[e+4] - mean) * rs * g1[e] + b1[e];
  }
}

// ---------------- K01: fused weight transpose + slots init + k1 features pass ----------------
// k1 segment: rows processed in two halves of 8; each half PRELOADS all 8 rows'
// feature data + prev_attn into registers (independent loads issued back-to-back,
// hiding HBM latency), then runs the LN+accumulate bodies in the ORIGINAL ascending
// rr order -> arithmetic order bit-identical to round 12. Cross-wave staged reduce
// unchanged. Plain __launch_bounds__(512): r10's (512,6) spilled acc to scratch.
struct K0Args {
  const float* src[9];
  unsigned short* dst[9];
  int K[9], N[9];
  const float* mu; const float* ls; const float* noise; float* S0;
  const float* features; const float* prev_attn;
  const float* g_in; const float* b_in; float* pf_part;
};

__global__ __launch_bounds__(512) void k01_kernel(K0Args a){
  __shared__ union {
    float tile[64][65];                                   // 16.6 KB (transpose)
    struct { float red2[2][8][512]; float tmp[8][512]; } r; // 32 + 16 = 48 KB (k1)
  } sm;
  int seg = blockIdx.y;
  int tid = threadIdx.x;
  if (seg < 9){
    // weight transpose: [K][N] fp32 -> [N][K] bf16 (512 threads, elementwise)
    int K = a.K[seg], N = a.N[seg];
    int tpn = N >> 6;
    int tiles = (K >> 6) * tpn;
    int t = blockIdx.x;
    if (t >= tiles) return;
    int k0 = (t / tpn) << 6, n0 = (t % tpn) << 6;
    const float* src = a.src[seg];
    #pragma unroll
    for (int i = 0; i < 8; ++i){
      int idx = tid + (i << 9);
      int r = idx >> 6, c = idx & 63;
      sm.tile[r][c] = src[(size_t)(k0 + r) * N + n0 + c];
    }
    __syncthreads();
    unsigned short* dst = a.dst[seg];
    #pragma unroll
    for (int i = 0; i < 8; ++i){
      int idx = tid + (i << 9);
      int r = idx >> 6, c = idx & 63;
      dst[(size_t)(n0 + r) * K + k0 + c] = f2bf(sm.tile[c][r]);
    }
  } else if (seg == 9){
    // slots init: S0 = mu + exp(log_sigma) * noise (256-thread mapping preserved)
    if (tid >= 256) return;
    long idx0 = ((long)blockIdx.x << 11) + ((long)tid << 3);
    if (idx0 >= 131072) return;
    int d0 = (int)(idx0 & 511);
    #pragma unroll
    for (int e = 0; e < 8; ++e){
      a.S0[idx0 + e] = a.mu[d0 + e] + expf(a.ls[d0 + e]) * a.noise[idx0 + e];
    }
  } else {
    // k1: features layernorm + pa-weighted partial sums
    if (blockIdx.x >= 256) return;
    int w = tid >> 6, lane = tid & 63;
    int b = blockIdx.x >> 3, sege = blockIdx.x & 7;
    int c8 = lane << 3;
    float gv[8], bv[8];
    #pragma unroll
    for (int e = 0; e < 8; ++e){ gv[e] = a.g_in[c8 + e]; bv[e] = a.b_in[c8 + e]; }
    float acc[8][8];
    #pragma unroll
    for (int p = 0; p < 8; ++p)
      #pragma unroll
      for (int e = 0; e < 8; ++e) acc[p][e] = 0.f;

    // two halves of 8 rows; preload then process in original rr order
    #pragma unroll
    for (int hh = 0; hh < 2; ++hh){
      float xs[8][8];
      f32x4 pa0[8], pa1[8];
      #pragma unroll
      for (int q = 0; q < 8; ++q){
        int rr = (hh << 3) + q;
        int j = (sege << 7) + (rr << 3) + w;
        load8(a.features + ((size_t)(b << 10) + j) * 512 + c8, xs[q]);
        const float* par = a.prev_attn + (((size_t)(b << 10) + j) << 3);
        pa0[q] = *(const f32x4*)par;
        pa1[q] = *(const f32x4*)(par + 4);
      }
      #pragma unroll
      for (int q = 0; q < 8; ++q){
        float s = 0.f, ss = 0.f;
        #pragma unroll
        for (int e = 0; e < 8; ++e){ s += xs[q][e]; ss += xs[q][e]*xs[q][e]; }
        s = wredsum(s); ss = wredsum(ss);
        float mean = s * (1.f/512.f);
        float rs = rsqrtf(ss * (1.f/512.f) - mean*mean + 1e-5f);
        float y[8];
        #pragma unroll
        for (int e = 0; e < 8; ++e) y[e] = (xs[q][e] - mean) * rs * gv[e] + bv[e];
        #pragma unroll
        for (int p = 0; p < 4; ++p)
          #pragma unroll
          for (int e = 0; e < 8; ++e) acc[p][e] += pa0[q][p] * y[e];
        #pragma unroll
        for (int p = 0; p < 4; ++p)
          #pragma unroll
          for (int e = 0; e < 8; ++e) acc[p + 4][e] += pa1[q][p] * y[e];
      }
    }
    // staged reduce: stage st folds waves 2st, 2st+1 into tmp in ascending order.
    // tmp after st: (((r0+r1)+r2)+...+r(2st+1)  == original left-to-right chain.
    for (int st = 0; st < 4; ++st){
      if ((w >> 1) == st){
        int h = w & 1;
        #pragma unroll
        for (int p = 0; p < 8; ++p){
          f32x4 a0 = {acc[p][0], acc[p][1], acc[p][2], acc[p][3]};
          f32x4 a1 = {acc[p][4], acc[p][5], acc[p][6], acc[p][7]};
          *(f32x4*)&sm.r.red2[h][p][c8] = a0;
          *(f32x4*)&sm.r.red2[h][p][c8 + 4] = a1;
        }
      }
      __syncthreads();
      for (int t2 = tid; t2 < 4096; t2 += 512){
        int p = t2 >> 9, d = t2 & 511;
        float t = (st == 0) ? sm.r.red2[0][p][d]
                            : (sm.r.tmp[p][d] + sm.r.red2[0][p][d]);
        t = t + sm.r.red2[1][p][d];
        sm.r.tmp[p][d] = t;
      }
      __syncthreads();
    }
    for (int t2 = tid; t2 < 4096; t2 += 512){
      int p = t2 >> 9, d = t2 & 511;
      a.pf_part[((size_t)((b << 3) + sege) * 8 + p) * 512 + d] = sm.r.tmp[p][d];
    }
  }
}

// ---------------- K2: reduce pf, pv = pf@Wv, k_ = ln(prev_slots)@Wk ----------------
__global__ __launch_bounds__(512) void k2_kernel(
    const float* __restrict__ pf_part, const float* __restrict__ prev_slots,
    const float* __restrict__ g_ps, const float* __restrict__ b_ps,
    const unsigned short* __restrict__ wvT, const unsigned short* __restrict__ wkT,
    float* __restrict__ pv, float* __restrict__ kbuf)
{
  __shared__ unsigned short pfB[16][512];
  __shared__ unsigned short psB[16][512];
  int tid = threadIdx.x, w = tid >> 6, lane = tid & 63, c8 = lane << 3;
  int blk = blockIdx.x;
  for (int t2 = tid; t2 < 1024; t2 += 512){
    int r = t2 >> 6, c = t2 & 63;
    int b = (blk << 1) + (r >> 3), p = r & 7;
    f32x4 s0 = {0,0,0,0}, s1 = {0,0,0,0};
    #pragma unroll
    for (int sg = 0; sg < 8; ++sg){
      const float* src = pf_part + ((size_t)((b << 3) + sg) * 8 + p) * 512 + (c << 3);
      s0 += *(const f32x4*)src;
      s1 += *(const f32x4*)(src + 4);
    }
    u16x8 pk;
    #pragma unroll
    for (int e = 0; e < 4; ++e){ pk[e] = f2bf(s0[e]); pk[e + 4] = f2bf(s1[e]); }
    *(u16x8*)&pfB[r][(c ^ (r & 7)) << 3] = pk;
  }
  #pragma unroll
  for (int rr = 0; rr < 2; ++rr){
    int r = (w << 1) + rr;
    int b = (blk << 1) + (r >> 3), sl = r & 7;
    float x[8];
    load8(prev_slots + ((size_t)((b << 3) + sl) << 9) + c8, x);
    ln8(x, g_ps, b_ps, c8);
    *(u16x8*)&psB[r][(lane ^ (r & 7)) << 3] = pack8(x);
  }
  __syncthreads();
  int which = w >> 2;
  int nbase = (w & 3) << 7;
  const unsigned short* Wt = which ? wkT : wvT;
  int l15 = lane & 15, kb4 = lane >> 4;
  f32x4 acc[8];
  #pragma unroll
  for (int nf = 0; nf < 8; ++nf) acc[nf] = (f32x4){0,0,0,0};
  for (int ks = 0; ks < 16; ++ks){
    int chunk = (ks << 2) + kb4;
    int m = l15;
    u16x8 av = which ? *(const u16x8*)&psB[m][(chunk ^ (m & 7)) << 3]
                     : *(const u16x8*)&pfB[m][(chunk ^ (m & 7)) << 3];
    #pragma unroll
    for (int nf = 0; nf < 8; ++nf){
      int n = nbase + (nf << 4) + l15;
      u16x8 bv = *(const u16x8*)(Wt + (size_t)n * 512 + (ks << 5) + (kb4 << 3));
      acc[nf] = mfma16(av, bv, acc[nf]);
    }
  }
  float* dst = which ? kbuf : pv;
  #pragma unroll
  for (int nf = 0; nf < 8; ++nf)
    #pragma unroll
    for (int ri = 0; ri < 4; ++ri){
      int r = (kb4 << 2) + ri;
      int b = (blk << 1) + (r >> 3);
      dst[((size_t)((b << 3) + (r & 7)) << 9) + nbase + (nf << 4) + l15] = acc[nf][ri];
    }
}

// ---------------- KA: per-2-batch step head (round-7 verbatim) ----------------
__global__ __launch_bounds__(512) void ka_kernel(
    const float* __restrict__ Sin, int step,
    const float* __restrict__ gfin, const float* __restrict__ bfin,
    const float* __restrict__ gs, const float* __restrict__ bs,
    const float* __restrict__ gica, const float* __restrict__ bica,
    const float* __restrict__ ga, const float* __restrict__ ba,
    const unsigned short* __restrict__ wqT,
    const float* __restrict__ kbuf, const float* __restrict__ pvbuf,
    const float* __restrict__ prev_attn,
    float* __restrict__ S1, unsigned short* __restrict__ hA,
    float* __restrict__ attn_out)
{
  __shared__ unsigned short lnS[16][512];
  __shared__ float Sf[16][512];
  __shared__ float qf[16][512];
  __shared__ float dotsS[2][8][8];
  __shared__ float attnS[2][8][8];
  int tid = threadIdx.x, w = tid >> 6, lane = tid & 63, c8 = lane << 3;
  int blk = blockIdx.x;

  // phase 1: load + (ln_fin) + ln_s
  #pragma unroll
  for (int rr = 0; rr < 2; ++rr){
    int r = (w << 1) + rr;
    int b = (blk << 1) + (r >> 3), sl = r & 7;
    float x[8];
    load8(Sin + ((size_t)((b << 3) + sl) << 9) + c8, x);
    if (step > 0) ln8(x, gfin, bfin, c8);
    store8(&Sf[r][c8], x);
    float z[8];
    #pragma unroll
    for (int e = 0; e < 8; ++e) z[e] = x[e];
    ln8(z, gs, bs, c8);
    *(u16x8*)&lnS[r][(lane ^ (r & 7)) << 3] = pack8(z);
  }
  __syncthreads();

  // phase 2: q = lnS @ WqT  (each wave: 64 cols)
  {
    int n0 = w << 6, l15 = lane & 15, kb4 = lane >> 4;
    f32x4 acc[4];
    #pragma unroll
    for (int nf = 0; nf < 4; ++nf) acc[nf] = (f32x4){0,0,0,0};
    for (int ks = 0; ks < 16; ++ks){
      int m = l15, chunk = (ks << 2) + kb4;
      u16x8 av = *(const u16x8*)&lnS[m][(chunk ^ (m & 7)) << 3];
      #pragma unroll
      for (int nf = 0; nf < 4; ++nf){
        int n = n0 + (nf << 4) + l15;
        u16x8 bv = *(const u16x8*)(wqT + (size_t)n * 512 + (ks << 5) + (kb4 << 3));
        acc[nf] = mfma16(av, bv, acc[nf]);
      }
    }
    #pragma unroll
    for (int nf = 0; nf < 4; ++nf)
      #pragma unroll
      for (int ri = 0; ri < 4; ++ri)
        qf[(kb4 << 2) + ri][n0 + (nf << 4) + l15] = acc[nf][ri];
  }
  __syncthreads();

  // phase 3: dots = q . k_ * scale
  if (tid < 128){
    int bb = tid >> 6, i = (tid >> 3) & 7, j = tid & 7;
    int b = (blk << 1) + bb;
    const float* kr = kbuf + ((size_t)((b << 3) + j) << 9);
    const float* qr = &qf[(bb << 3) + i][0];
    float s = 0.f;
    for (int d = 0; d < 512; d += 4){
      f32x4 qv = *(const f32x4*)(qr + d);
      f32x4 kv = *(const f32x4*)(kr + d);
      s += qv[0]*kv[0] + qv[1]*kv[1] + qv[2]*kv[2] + qv[3]*kv[3];
    }
    dotsS[bb][i][j] = s * 0.044194173824159216f;
  }
  __syncthreads();

  // phase 4: softmax over slot axis (i), per (bb, j), + EPS
  if (tid < 16){
    int bb = tid >> 3, j = tid & 7;
    float mx = -1e30f;
    #pragma unroll
    for (int i = 0; i < 8; ++i) mx = fmaxf(mx, dotsS[bb][i][j]);
    float ex[8]; float sum = 0.f;
    #pragma unroll
    for (int i = 0; i < 8; ++i){ ex[i] = expf(dotsS[bb][i][j] - mx); sum += ex[i]; }
    float inv = 1.f / sum;
    #pragma unroll
    for (int i = 0; i < 8; ++i) attnS[bb][i][j] = ex[i] * inv + 1e-8f;
  }
  __syncthreads();

  // phase 5: renormalize over j
  if (tid < 16){
    int bb = tid >> 3, i = tid & 7;
    float s = 0.f;
    #pragma unroll
    for (int j = 0; j < 8; ++j) s += attnS[bb][i][j];
    float inv = 1.f / s;
    #pragma unroll
    for (int j = 0; j < 8; ++j) attnS[bb][i][j] *= inv;
  }
  __syncthreads();

  // phase 6: upd + S1 + hA
  #pragma unroll
  for (int rr = 0; rr < 2; ++rr){
    int r = (w << 1) + rr;
    int bb = r >> 3; int b = (blk << 1) + bb; int i = r & 7;
    float u[8];
    #pragma unroll
    for (int e = 0; e < 8; ++e) u[e] = 0.f;
    #pragma unroll
    for (int p = 0; p < 8; ++p){
      float ap = attnS[bb][i][p];
      const float* pvr = pvbuf + ((size_t)((b << 3) + p) << 9) + c8;
      f32x4 v0 = *(const f32x4*)pvr, v1 = *(const f32x4*)(pvr + 4);
      #pragma unroll
      for (int e = 0; e < 4; ++e){ u[e] += ap * v0[e]; u[e + 4] += ap * v1[e]; }
    }
    float x[8];
    #pragma unroll
    for (int e = 0; e < 8; ++e) x[e] = Sf[r][c8 + e] + u[e];
    ln8(x, gica, bica, c8);
    store8(S1 + ((size_t)((b << 3) + i) << 9) + c8, x);
    ln8(x, ga, ba, c8);
    *(u16x8*)(hA + ((size_t)((b << 3) + i) << 9) + c8) = pack8(x);
  }

  // phase 7: final attention map output: out[b][jhw][i] = sum_p attn[i][p] * prev_attn[b][jhw][p]
  if (attn_out){
    for (int t2 = tid; t2 < 2048; t2 += 512){
      int bb = t2 >> 10, jh = t2 & 1023;
      int b = (blk << 1) + bb;
      const float* par = prev_attn + (((size_t)(b << 10) + jh) << 3);
      f32x4 p0 = *(const f32x4*)par, p1 = *(const f32x4*)(par + 4);
      float o[8];
      #pragma unroll
      for (int i2 = 0; i2 < 8; ++i2){
        float s = 0.f;
        #pragma unroll
        for (int p = 0; p < 4; ++p){
          s += attnS[bb][i2][p] * p0[p];
          s += attnS[bb][i2][p + 4] * p1[p];
        }
        o[i2] = s;
      }
      float* dst = attn_out + (((size_t)(b << 10) + jh) << 3);
      store8(dst, o);
    }
  }
}

// ---------------- MHSA: per (batch, head), 8x8 attention over slots ----------------
__global__ __launch_bounds__(64) void mhsa_kernel(
    const unsigned short* __restrict__ qkv, unsigned short* __restrict__ ob)
{
  int b = blockIdx.x >> 3, h = blockIdx.x & 7;
  int lane = threadIdx.x;
  int i = lane >> 3, j = lane & 7;
  const unsigned short* qr = qkv + (size_t)((b << 3) + i) * 1536 + (h << 6);
  const unsigned short* kr = qkv + (size_t)((b << 3) + j) * 1536 + 512 + (h << 6);
  float s = 0.f;
  #pragma unroll
  for (int d0 = 0; d0 < 64; d0 += 8){
    u16x8 qv = *(const u16x8*)(qr + d0);
    u16x8 kv = *(const u16x8*)(kr + d0);
    #pragma unroll
    for (int e = 0; e < 8; ++e) s += bf2f(qv[e]) * bf2f(kv[e]);
  }
  s *= 0.125f;
  float mx = s;
  mx = fmaxf(mx, __shfl_xor(mx, 1, 64));
  mx = fmaxf(mx, __shfl_xor(mx, 2, 64));
  mx = fmaxf(mx, __shfl_xor(mx, 4, 64));
  float p = expf(s - mx);
  float den = p;
  den += __shfl_xor(den, 1, 64);
  den += __shfl_xor(den, 2, 64);
  den += __shfl_xor(den, 4, 64);
  float att = p / den;
  int dg = lane & 7;
  float acc[8];
  #pragma unroll
  for (int e = 0; e < 8; ++e) acc[e] = 0.f;
  #pragma unroll
  for (int jj = 0; jj < 8; ++jj){
    float av = __shfl(att, (lane & 56) | jj, 64);
    const unsigned short* vr = qkv + (size_t)((b << 3) + jj) * 1536 + 1024 + (h << 6) + (dg << 3);
    u16x8 vv = *(const u16x8*)vr;
    #pragma unroll
    for (int e = 0; e < 8; ++e) acc[e] += av * bf2f(vv[e]);
  }
  u16x8 o8;
  #pragma unroll
  for (int e = 0; e < 8; ++e) o8[e] = f2bf(acc[e]);
  *(u16x8*)(ob + (size_t)((b << 3) + i) * 512 + (h << 6) + (dg << 3)) = o8;
}

// ---------------- gemm16: 16-row tile, full-K in-thread (bit-identical K-order) ----------------
// AMODE: 0 = plain bf16 A [256][K]; 1 = layernorm from fp32 [256][512]
// EPMODE: 0 = bf16 store; 1 = bf16 + bias; 2 = fp32 resid + v + bias
// NF: n-fragments per wave (block covers 64*NF cols)
template<int AMODE, int EPMODE, int NF>
__global__ __launch_bounds__(256) void gemm16_kernel(
    const void* __restrict__ Asrc, const unsigned short* __restrict__ Wt,
    void* __restrict__ Cdst, const float* __restrict__ resid,
    const float* __restrict__ bias, const float* __restrict__ g,
    const float* __restrict__ bp, int N, int K)
{
  __shared__ unsigned short Alds[16][512];
  int tid = threadIdx.x, lane = tid & 63, w = tid >> 6, c8 = lane << 3;
  int m0 = blockIdx.y << 4;
  int n0g = blockIdx.x * (64 * NF);
  int l15 = lane & 15, kb4 = lane >> 4;
  f32x4 acc[NF];
  #pragma unroll
  for (int nf = 0; nf < NF; ++nf) acc[nf] = (f32x4){0,0,0,0};

  int nkc = K >> 9;
  for (int kc = 0; kc < nkc; ++kc){
    if (kc) __syncthreads();
    if (AMODE == 0){
      const unsigned short* A = (const unsigned short*)Asrc;
      #pragma unroll
      for (int rr = 0; rr < 4; ++rr){
        int r = (w << 2) + rr;
        u16x8 v = *(const u16x8*)(A + (size_t)(m0 + r) * K + (kc << 9) + c8);
        *(u16x8*)&Alds[r][(lane ^ (r & 7)) << 3] = v;
      }
    } else {
      const float* A = (const float*)Asrc;
      #pragma unroll
      for (int rr = 0; rr < 4; ++rr){
        int r = (w << 2) + rr;
        float x[8];
        load8(A + ((size_t)(m0 + r) << 9) + c8, x);
        ln8(x, g, bp, c8);
        *(u16x8*)&Alds[r][(lane ^ (r & 7)) << 3] = pack8(x);
      }
    }
    __syncthreads();
    const unsigned short* wbase = Wt + ((size_t)kc << 9);
    for (int ks = 0; ks < 16; ++ks){
      int chunk = (ks << 2) + kb4;
      u16x8 a0 = *(const u16x8*)&Alds[l15][(chunk ^ (l15 & 7)) << 3];
      #pragma unroll
      for (int nf = 0; nf < NF; ++nf){
        int n = n0g + w * (16 * NF) + (nf << 4) + l15;
        u16x8 bv = *(const u16x8*)(wbase + (size_t)n * K + (ks << 5) + (kb4 << 3));
        acc[nf] = mfma16(a0, bv, acc[nf]);
      }
    }
  }
  #pragma unroll
  for (int nf = 0; nf < NF; ++nf)
    #pragma unroll
    for (int ri = 0; ri < 4; ++ri){
      int m = m0 + (kb4 << 2) + ri;
      int c = n0g + w * (16 * NF) + (nf << 4) + l15;
      float v = acc[nf][ri];
      if (EPMODE == 0){
        ((unsigned short*)Cdst)[(size_t)m * N + c] = f2bf(v);
      } else if (EPMODE == 1){
        ((unsigned short*)Cdst)[(size_t)m * N + c] = f2bf(v + bias[c]);
      } else {
        ((float*)Cdst)[(size_t)m * N + c] = resid[(size_t)m * N + c] + v + bias[c];
      }
    }
}

// ---------------- ff2: full-K single-barrier; S3 = S2 + swiglu(hw1) @ Wff2 + bff2 ----------------
__global__ __launch_bounds__(256) void ff2_kernel(
    const unsigned short* __restrict__ hw1, const unsigned short* __restrict__ wff2T,
    float* __restrict__ S3, const float* __restrict__ S2, const float* __restrict__ bff2)
{
  __shared__ unsigned short Alds[16][2048]; // 64 KB
  int tid = threadIdx.x, lane = tid & 63, w = tid >> 6, c8 = lane << 3;
  int m0 = blockIdx.y << 4;
  int n0 = blockIdx.x << 6;

  #pragma unroll
  for (int kc = 0; kc < 4; ++kc){
    #pragma unroll
    for (int rr = 0; rr < 4; ++rr){
      int r = (w << 2) + rr;
      const unsigned short* ar = hw1 + (size_t)(m0 + r) * 4096 + (kc << 9) + c8;
      u16x8 uu = *(const u16x8*)ar;
      u16x8 gg = *(const u16x8*)(ar + 2048);
      u16x8 pk;
      #pragma unroll
      for (int e = 0; e < 8; ++e){
        float uv = bf2f(uu[e]), gv = bf2f(gg[e]);
        float sl = gv / (1.f + __expf(-gv));
        pk[e] = f2bf(uv * sl);
      }
      *(u16x8*)&Alds[r][(kc << 9) + ((lane ^ (r & 7)) << 3)] = pk;
    }
  }
  __syncthreads();

  int l15 = lane & 15, kb4 = lane >> 4;
  f32x4 acc = {0,0,0,0};
  for (int kk = 0; kk < 64; ++kk){
    int kc = kk >> 4, ks = kk & 15;
    int chunk = (ks << 2) + kb4;
    u16x8 a0 = *(const u16x8*)&Alds[l15][(kc << 9) + ((chunk ^ (l15 & 7)) << 3)];
    int n = n0 + (w << 4) + l15;
    u16x8 bv = *(const u16x8*)(wff2T + (size_t)n * 2048 + (kc << 9) + (ks << 5) + (kb4 << 3));
    acc = mfma16(a0, bv, acc);
  }
  #pragma unroll
  for (int ri = 0; ri < 4; ++ri){
    int m = m0 + (kb4 << 2) + ri;
    int c = n0 + (w << 4) + l15;
    S3[(size_t)m * 512 + c] = S2[(size_t)m * 512 + c] + acc[ri] + bff2[c];
  }
}

// ---------------- final: out_slots = ln(S3, g_fin, b_fin) ----------------
__global__ __launch_bounds__(512) void fin_kernel(
    const float* __restrict__ S3, const float* __restrict__ g,
    const float* __restrict__ bp, float* __restrict__ out)
{
  int tid = threadIdx.x, w = tid >> 6, lane = tid & 63, c8 = lane << 3;
  int row = (blockIdx.x << 3) + w;
  float x[8];
  load8(S3 + ((size_t)row << 9) + c8, x);
  ln8(x, g, bp, c8);
  store8(out + ((size_t)row << 9) + c8, x);
}

// ---------------- host ----------------
extern "C" void kernel_launch(void* const* d_in, const int* in_sizes, int n_in,
                              void* d_out, int out_size, void* d_ws, size_t ws_size,
                              hipStream_t stream)
{
  (void)in_sizes; (void)n_in; (void)out_size; (void)ws_size;
  const float* features       = (const float*)d_in[0];
  const float* prev_slots     = (const float*)d_in[1];
  const float* prev_attn      = (const float*)d_in[2];
  const float* init_noise     = (const float*)d_in[3];
  const float* init_mu        = (const float*)d_in[4];
  const float* init_log_sigma = (const float*)d_in[5];
  const float* Wk   = (const float*)d_in[6];
  const float* Wv   = (const float*)d_in[7];
  const float* Wq   = (const float*)d_in[8];
  const float* g_in = (const float*)d_in[9];
  const float* g_ps = (const float*)d_in[10];
  const float* g_s  = (const float*)d_in[11];
  const float* g_ica= (const float*)d_in[12];
  const float* g_a  = (const float*)d_in[13];
  const float* g_f  = (const float*)d_in[14];
  const float* g_fin= (const float*)d_in[15];
  const float* b_in = (const float*)d_in[16];
  const float* b_ps = (const float*)d_in[17];
  const float* b_s  = (const float*)d_in[18];
  const float* b_ica= (const float*)d_in[19];
  const float* b_a  = (const float*)d_in[20];
  const float* b_f  = (const float*)d_in[21];
  const float* b_fin= (const float*)d_in[22];
  const float* Waq  = (const float*)d_in[23];
  const float* Wak  = (const float*)d_in[24];
  const float* Wav  = (const float*)d_in[25];
  const float* Wao  = (const float*)d_in[26];
  const float* bao  = (const float*)d_in[27];
  const float* Wff1 = (const float*)d_in[28];
  const float* bff1 = (const float*)d_in[29];
  const float* Wff2 = (const float*)d_in[30];
  const float* bff2 = (const float*)d_in[31];

  char* wsb = (char*)d_ws;
  size_t off = 0;
  auto alloc = [&](size_t n) -> void* {
    void* p = wsb + off;
    off = (off + n + 255) & ~(size_t)255;
    return p;
  };
  unsigned short* wkT   = (unsigned short*)alloc(512 * 512 * 2);
  unsigned short* wvT   = (unsigned short*)alloc(512 * 512 * 2);
  unsigned short* wqT   = (unsigned short*)alloc(512 * 512 * 2);
  unsigned short* wqkvT = (unsigned short*)alloc((size_t)3 * 512 * 512 * 2); // waq|wak|wav
  unsigned short* waoT  = (unsigned short*)alloc(512 * 512 * 2);
  unsigned short* wff1T = (unsigned short*)alloc((size_t)4096 * 512 * 2);
  unsigned short* wff2T = (unsigned short*)alloc((size_t)512 * 2048 * 2);
  float* S0 = (float*)alloc((size_t)256 * 512 * 4);
  float* S3 = (float*)alloc((size_t)256 * 512 * 4);
  float* S1 = (float*)alloc((size_t)256 * 512 * 4);
  float* S2 = (float*)alloc((size_t)256 * 512 * 4);
  unsigned short* hA   = (unsigned short*)alloc((size_t)256 * 512 * 2);
  unsigned short* qkvB = (unsigned short*)alloc((size_t)256 * 1536 * 2);
  unsigned short* oB   = (unsigned short*)alloc((size_t)256 * 512 * 2);
  float* pfp = (float*)alloc((size_t)32 * 8 * 8 * 512 * 4);   // 4 MB; dead after k2
  unsigned short* hw1 = (unsigned short*)pfp;                 // alias: 256*4096*2 = 2 MB
  float* pvB = (float*)alloc((size_t)32 * 8 * 512 * 4);
  float* kB  = (float*)alloc((size_t)32 * 8 * 512 * 4);

  K0Args a{};
  a.src[0] = Wk;   a.dst[0] = wkT;                    a.K[0] = 512;  a.N[0] = 512;
  a.src[1] = Wv;   a.dst[1] = wvT;                    a.K[1] = 512;  a.N[1] = 512;
  a.src[2] = Wq;   a.dst[2] = wqT;                    a.K[2] = 512;  a.N[2] = 512;
  a.src[3] = Waq;  a.dst[3] = wqkvT;                  a.K[3] = 512;  a.N[3] = 512;
  a.src[4] = Wak;  a.dst[4] = wqkvT + 512 * 512;      a.K[4] = 512;  a.N[4] = 512;
  a.src[5] = Wav;  a.dst[5] = wqkvT + 2 * 512 * 512;  a.K[5] = 512;  a.N[5] = 512;
  a.src[6] = Wao;  a.dst[6] = waoT;                   a.K[6] = 512;  a.N[6] = 512;
  a.src[7] = Wff1; a.dst[7] = wff1T;                  a.K[7] = 512;  a.N[7] = 4096;
  a.src[8] = Wff2; a.dst[8] = wff2T;                  a.K[8] = 2048; a.N[8] = 512;
  a.mu = init_mu; a.ls = init_log_sigma; a.noise = init_noise; a.S0 = S0;
  a.features = features; a.prev_attn = prev_attn;
  a.g_in = g_in; a.b_in = b_in; a.pf_part = pfp;

  // fused prologue: weight transposes + slots init + k1 features pass (independent work)
  k01_kernel<<<dim3(512, 11), 512, 0, stream>>>(a);
  k2_kernel<<<16, 512, 0, stream>>>(pfp, prev_slots, g_ps, b_ps, wvT, wkT, pvB, kB);

  float* outSlots = (float*)d_out;
  float* outAttn  = (float*)d_out + 131072;

  for (int step = 0; step < 4; ++step){
    ka_kernel<<<16, 512, 0, stream>>>(step ? S3 : S0, step,
        g_fin, b_fin, g_s, b_s, g_ica, b_ica, g_a, b_a,
        wqT, kB, pvB, prev_attn, S1, hA,
        (step == 3) ? outAttn : (float*)nullptr);
    // qkv: [256,512] @ [512,1536] -> bf16 (16x64 tiles, 384 blocks)
    gemm16_kernel<0,0,1><<<dim3(24, 16), 256, 0, stream>>>(
        hA, wqkvT, qkvB, nullptr, nullptr, nullptr, nullptr, 1536, 512);
    mhsa_kernel<<<256, 64, 0, stream>>>(qkvB, oB);
    // ao: S2 = S1 + oB @ Wao + bao (64-wide tiles, 128 blocks)
    gemm16_kernel<0,2,1><<<dim3(8, 16), 256, 0, stream>>>(
        oB, waoT, S2, S1, bao, nullptr, nullptr, 512, 512);
    // ff1: ln(S2) @ [512,4096] + bff1 -> bf16 hw1 (16x64 tiles, 1024 blocks)
    gemm16_kernel<1,1,1><<<dim3(64, 16), 256, 0, stream>>>(
        S2, wff1T, hw1, nullptr, bff1, g_f, b_f, 4096, 512);
    // ff2: S3 = S2 + swiglu(hw1) @ [2048,512] + bff2 (full-K stage, 128 blocks)
    ff2_kernel<<<dim3(8, 16), 256, 0, stream>>>(hw1, wff2T, S3, S2, bff2);
  }
  fin_kernel<<<32, 512, 0, stream>>>(S3, g_fin, b_fin, outSlots);
}